// Round 5
// baseline (62.237 us; speedup 1.0000x reference)
//
#include <hip/hip_runtime.h>
#include <hip/hip_bf16.h>

// AttentionNTKChoiceModel — MFMA bf16-split, low-sync structure.
// B=32, L=512, D=128, H=8, D0=D2=32.
//
// convert: X[16384,128]f32 -> X2[16384,256]bf16  (cols 0..127 hi, 128..255 lo)
//          Wc[576,256]bf16: rows W1(0..255), W2(256..511), u(512..519), 0-pad
//          u_h = sum_d w[h,d]*W3[h*32+d,:]/sqrt(8)
// proj:    acc = X2 . Wc[diag chunk] + X2 . Wc[chunk+128 mod 256]
//          (diag = hh+ll, shifted = hl+lh -> exact f32 product). 128x64 tile.
//          Epilogue re-splits into per-head Q2/K2 [B,H,L,64]bf16
//          (d 0..31 hi, 32..63 lo; Q pre-scaled 1/sqrt(32)*log2e), Vw[B,H,L]f32.
// attn:    per (b,h,256q): whole 512-key head staged in LDS once (1 barrier),
//          scores^T = K @ Q^T 3-term (hh+hl+lh), online softmax in exp2
//          domain, val += p*Vw -> vws[B,H,L]
// final:   sum heads, q-mask, 512-wide softmax per batch row.

typedef __attribute__((ext_vector_type(8))) short bf16x8;
typedef __attribute__((ext_vector_type(4))) float f32x4;
typedef __attribute__((ext_vector_type(8))) unsigned short ushort8;
typedef __attribute__((ext_vector_type(4))) unsigned short ushort4v;

#define NEG (-10000.0f)
#define LOG2E 1.4426950408889634f
#define QSCALE (0.17677669529663687f * LOG2E)

__device__ __forceinline__ unsigned short bf16_rn(float x, float* rep) {
  unsigned u = __float_as_uint(x);
  unsigned r = (u + 0x7FFFu + ((u >> 16) & 1u)) >> 16;
  *rep = __uint_as_float(r << 16);
  return (unsigned short)r;
}

// grid 1057 x 256: [0,1024) X-split, [1024,1056) W1/W2-split, 1056 u+pad
__global__ __launch_bounds__(256) void convert_kernel(
    const float* __restrict__ X, const float* __restrict__ W1,
    const float* __restrict__ W2, const float* __restrict__ W3,
    const float* __restrict__ w,
    unsigned short* __restrict__ X2, unsigned short* __restrict__ Wc) {
  const int bx = blockIdx.x, t = threadIdx.x;
  if (bx < 1056) {
    const float* src;
    unsigned short* dst;
    int row, c;
    if (bx < 1024) {
      const size_t flat = (size_t)bx * 2048 + t * 8;
      row = (int)(flat >> 7); c = (int)(flat & 127);
      src = &X[flat];
      dst = &X2[(size_t)row * 256 + c];
    } else {
      const int flat = (bx - 1024) * 2048 + t * 8;
      row = flat >> 7; c = flat & 127;
      src = (row < 256) ? &W1[(size_t)row * 128 + c]
                        : &W2[(size_t)(row - 256) * 128 + c];
      dst = &Wc[(size_t)row * 256 + c];
    }
    float xv[8];
    *(float4*)&xv[0] = *(const float4*)src;
    *(float4*)&xv[4] = *(const float4*)(src + 4);
    ushort8 hi, lo;
#pragma unroll
    for (int i = 0; i < 8; ++i) {
      float hf, lf;
      hi[i] = bf16_rn(xv[i], &hf);
      lo[i] = bf16_rn(xv[i] - hf, &lf);
    }
    *(ushort8*)dst = hi;
    *(ushort8*)(dst + 128) = lo;
  } else {
    __shared__ float uS[8][128];
    if (t < 128) {
#pragma unroll
      for (int h = 0; h < 8; ++h) {
        float acc = 0.f;
#pragma unroll
        for (int d = 0; d < 32; ++d)
          acc += W3[(h * 32 + d) * 128 + t] * w[h * 32 + d];
        uS[h][t] = acc * 0.3535533905932738f;  // 1/sqrt(8)
      }
    }
    __syncthreads();
    {
      const int r = t >> 5, c = (t & 31) * 4;
      float4 v = *(float4*)&uS[r][c];
      float vv[4] = {v.x, v.y, v.z, v.w};
      ushort4v hi, lo;
#pragma unroll
      for (int i = 0; i < 4; ++i) {
        float hf, lf;
        hi[i] = bf16_rn(vv[i], &hf);
        lo[i] = bf16_rn(vv[i] - hf, &lf);
      }
      *(ushort4v*)&Wc[(size_t)(512 + r) * 256 + c] = hi;
      *(ushort4v*)&Wc[(size_t)(512 + r) * 256 + 128 + c] = lo;
    }
    const ushort8 z = {};
    for (int i = t; i < 1792; i += 256)  // zero rows 520..575
      *(ushort8*)&Wc[(size_t)520 * 256 + i * 8] = z;
  }
}

// [16384,576] GEMM, exact 4-term: diag (hh+ll) + shifted (hl+lh).
// Block 256thr (4 waves), tile 128x64, K chunks of 64 over the 256-wide [hi|lo].
// Wave w owns rows w*32..w*32+31 (2 16-row subtiles) x 64 cols.
__global__ __launch_bounds__(256) void proj_kernel(
    const unsigned short* __restrict__ X2, const unsigned short* __restrict__ Wc,
    unsigned short* __restrict__ Q2, unsigned short* __restrict__ K2,
    float* __restrict__ Vw) {
  // stride 72 ushort = 144B (36 dw, %8==4 -> 2-way max on frag reads)
  __shared__ unsigned short XS[128][72], WSd[64][72], WSx[64][72];
  const int t = threadIdx.x;
  const int row0 = blockIdx.x * 128, col0 = blockIdx.y * 64;
  const int w = t >> 6, lane = t & 63, g = lane >> 4, r16 = lane & 15;

  f32x4 acc[2][4];
#pragma unroll
  for (int mm = 0; mm < 2; ++mm)
#pragma unroll
    for (int n = 0; n < 4; ++n) acc[mm][n] = (f32x4){0.f, 0.f, 0.f, 0.f};

  for (int kc = 0; kc < 256; kc += 64) {
    const int kcx = (kc + 128) & 255;
    if (kc) __syncthreads();
    {
#pragma unroll
      for (int i = 0; i < 4; ++i) {  // X: 128 rows x 8 col-groups
        const int flat = i * 256 + t, row = flat >> 3, cg = (flat & 7) * 8;
        *(ushort8*)&XS[row][cg] =
            *(const ushort8*)&X2[(size_t)(row0 + row) * 256 + kc + cg];
      }
#pragma unroll
      for (int i = 0; i < 2; ++i) {  // W: 64 rows x 8 col-groups, 2 bufs
        const int flat = i * 256 + t, row = flat >> 3, cg = (flat & 7) * 8;
        const size_t wb = (size_t)(col0 + row) * 256;
        *(ushort8*)&WSd[row][cg] = *(const ushort8*)&Wc[wb + kc + cg];
        *(ushort8*)&WSx[row][cg] = *(const ushort8*)&Wc[wb + kcx + cg];
      }
    }
    __syncthreads();
#pragma unroll
    for (int ks = 0; ks < 2; ++ks) {
      bf16x8 ah[2];
#pragma unroll
      for (int mm = 0; mm < 2; ++mm)
        ah[mm] = *(const bf16x8*)&XS[w * 32 + mm * 16 + r16][ks * 32 + g * 8];
#pragma unroll
      for (int n = 0; n < 4; ++n) {
        bf16x8 bd = *(const bf16x8*)&WSd[n * 16 + r16][ks * 32 + g * 8];
        bf16x8 bx = *(const bf16x8*)&WSx[n * 16 + r16][ks * 32 + g * 8];
#pragma unroll
        for (int mm = 0; mm < 2; ++mm) {
          acc[mm][n] = __builtin_amdgcn_mfma_f32_16x16x32_bf16(ah[mm], bd, acc[mm][n], 0, 0, 0);
          acc[mm][n] = __builtin_amdgcn_mfma_f32_16x16x32_bf16(ah[mm], bx, acc[mm][n], 0, 0, 0);
        }
      }
    }
  }
  // C layout: row = w*32 + mm*16 + g*4 + r, col = col0 + n*16 + r16
#pragma unroll
  for (int n = 0; n < 4; ++n) {
    const int col = col0 + n * 16 + r16;
#pragma unroll
    for (int mm = 0; mm < 2; ++mm) {
#pragma unroll
      for (int r = 0; r < 4; ++r) {
        const int row = row0 + w * 32 + mm * 16 + g * 4 + r;
        const int b = row >> 9, l = row & 511;
        const float val = acc[mm][n][r];
        if (col < 256) {
          const float sv = val * QSCALE;
          float hf, lf;
          const unsigned short hb = bf16_rn(sv, &hf);
          const unsigned short lb = bf16_rn(sv - hf, &lf);
          const size_t o = ((size_t)(b * 8 + (col >> 5)) * 512 + l) * 64 + (col & 31);
          Q2[o] = hb; Q2[o + 32] = lb;
        } else if (col < 512) {
          const int c2 = col - 256;
          float hf, lf;
          const unsigned short hb = bf16_rn(val, &hf);
          const unsigned short lb = bf16_rn(val - hf, &lf);
          const size_t o = ((size_t)(b * 8 + (c2 >> 5)) * 512 + l) * 64 + (c2 & 31);
          K2[o] = hb; K2[o + 32] = lb;
        } else if (col < 520) {
          Vw[(size_t)(b * 8 + (col - 512)) * 512 + l] = val;
        }
      }
    }
  }
}

// Block (qhalf, h, b), 512 thr, ONE barrier: whole head's K/Vw/bias in LDS.
// Wave w owns 32 q rows (2 qtiles). 8 chunks of 64 keys, pure compute.
__global__ __launch_bounds__(512, 4) void attn_kernel(
    const unsigned short* __restrict__ Q2, const unsigned short* __restrict__ K2,
    const float* __restrict__ Vw, const int* __restrict__ mask,
    float* __restrict__ vws) {
  __shared__ unsigned short KS[512][72];  // 72 KB
  __shared__ float VwS[512], biasS[512];
  const int t = threadIdx.x;
  const int w = t >> 6, lane = t & 63, g = lane >> 4, r16 = lane & 15;
  const int qbase = blockIdx.x * 256, h = blockIdx.y, b = blockIdx.z;
  const size_t headoff = (size_t)(b * 8 + h) * 512;

  // stage whole head: linear in K2 -> perfectly coalesced
#pragma unroll
  for (int i = 0; i < 8; ++i) {
    const int flat = i * 512 + t;  // ushort8 index
    const int row = flat >> 3, cg = (flat & 7) * 8;
    *(ushort8*)&KS[row][cg] = *(const ushort8*)&K2[(headoff + row) * 64 + cg];
  }
  VwS[t] = Vw[headoff + t];
  biasS[t] = mask[b * 512 + t] ? 0.f : NEG * LOG2E;

  bf16x8 qf[2][2];  // [qtile][hi/lo]
#pragma unroll
  for (int qt = 0; qt < 2; ++qt)
#pragma unroll
    for (int ks = 0; ks < 2; ++ks)
      qf[qt][ks] = *(const bf16x8*)
          &Q2[(headoff + qbase + w * 32 + qt * 16 + r16) * 64 + ks * 32 + g * 8];

  __syncthreads();

  float m[2] = {-1e30f, -1e30f}, lsum[2] = {0.f, 0.f}, val[2] = {0.f, 0.f};

  for (int c = 0; c < 8; ++c) {
    bf16x8 a0[4], a1[4];  // K hi / K lo for 4 key-subtiles
#pragma unroll
    for (int j = 0; j < 4; ++j) {
      a0[j] = *(const bf16x8*)&KS[c * 64 + j * 16 + r16][g * 8];
      a1[j] = *(const bf16x8*)&KS[c * 64 + j * 16 + r16][32 + g * 8];
    }
    f32x4 sc[4][2];
#pragma unroll
    for (int j = 0; j < 4; ++j)
#pragma unroll
      for (int qt = 0; qt < 2; ++qt) {
        f32x4 z = (f32x4){0.f, 0.f, 0.f, 0.f};
        z = __builtin_amdgcn_mfma_f32_16x16x32_bf16(a0[j], qf[qt][0], z, 0, 0, 0);
        z = __builtin_amdgcn_mfma_f32_16x16x32_bf16(a0[j], qf[qt][1], z, 0, 0, 0);
        z = __builtin_amdgcn_mfma_f32_16x16x32_bf16(a1[j], qf[qt][0], z, 0, 0, 0);
        sc[j][qt] = z;
      }
#pragma unroll
    for (int qt = 0; qt < 2; ++qt) {
      float sb[4][4];
      float cmax = -1e30f;
#pragma unroll
      for (int j = 0; j < 4; ++j) {
        const float4 bsj = *(const float4*)&biasS[c * 64 + j * 16 + g * 4];
        sb[j][0] = sc[j][qt][0] + bsj.x;
        sb[j][1] = sc[j][qt][1] + bsj.y;
        sb[j][2] = sc[j][qt][2] + bsj.z;
        sb[j][3] = sc[j][qt][3] + bsj.w;
#pragma unroll
        for (int r = 0; r < 4; ++r) cmax = fmaxf(cmax, sb[j][r]);
      }
      cmax = fmaxf(cmax, __shfl_xor(cmax, 16));
      cmax = fmaxf(cmax, __shfl_xor(cmax, 32));
      const float mnew = fmaxf(m[qt], cmax);
      const float f = __builtin_amdgcn_exp2f(m[qt] - mnew);
      m[qt] = mnew;
      float ls = lsum[qt] * f, vv = val[qt] * f;
#pragma unroll
      for (int j = 0; j < 4; ++j) {
        const float4 vwj = *(const float4*)&VwS[c * 64 + j * 16 + g * 4];
        const float p0 = __builtin_amdgcn_exp2f(sb[j][0] - mnew);
        const float p1 = __builtin_amdgcn_exp2f(sb[j][1] - mnew);
        const float p2 = __builtin_amdgcn_exp2f(sb[j][2] - mnew);
        const float p3 = __builtin_amdgcn_exp2f(sb[j][3] - mnew);
        ls += (p0 + p1) + (p2 + p3);
        vv = fmaf(p0, vwj.x, vv);
        vv = fmaf(p1, vwj.y, vv);
        vv = fmaf(p2, vwj.z, vv);
        vv = fmaf(p3, vwj.w, vv);
      }
      lsum[qt] = ls; val[qt] = vv;
    }
  }
#pragma unroll
  for (int qt = 0; qt < 2; ++qt) {
    lsum[qt] += __shfl_xor(lsum[qt], 16);
    val[qt]  += __shfl_xor(val[qt], 16);
    lsum[qt] += __shfl_xor(lsum[qt], 32);
    val[qt]  += __shfl_xor(val[qt], 32);
  }
  if (lane < 16) {
#pragma unroll
    for (int qt = 0; qt < 2; ++qt)
      vws[headoff + qbase + w * 32 + qt * 16 + lane] = val[qt] / lsum[qt];
  }
}

__global__ __launch_bounds__(512) void final_kernel(
    const float* __restrict__ vws, const int* __restrict__ mask,
    float* __restrict__ out) {
  const int b = blockIdx.x, l = threadIdx.x;  // grid 32, block 512
  __shared__ float redm[8], reds[8];
  float v = 0.f;
#pragma unroll
  for (int h = 0; h < 8; ++h) v += vws[(size_t)(b * 8 + h) * 512 + l];
  if (mask[b * 512 + l] == 0) v = NEG;
  float mx = v;
#pragma unroll
  for (int off = 32; off >= 1; off >>= 1) mx = fmaxf(mx, __shfl_xor(mx, off));
  if ((l & 63) == 0) redm[l >> 6] = mx;
  __syncthreads();
  float M = redm[0];
#pragma unroll
  for (int i = 1; i < 8; ++i) M = fmaxf(M, redm[i]);
  const float e = __expf(v - M);
  float sm = e;
#pragma unroll
  for (int off = 32; off >= 1; off >>= 1) sm += __shfl_xor(sm, off);
  if ((l & 63) == 0) reds[l >> 6] = sm;
  __syncthreads();
  float S = 0.f;
#pragma unroll
  for (int i = 0; i < 8; ++i) S += reds[i];
  out[b * 512 + l] = e / S;
}

extern "C" void kernel_launch(void* const* d_in, const int* in_sizes, int n_in,
                              void* d_out, int out_size, void* d_ws, size_t ws_size,
                              hipStream_t stream) {
  const float* X  = (const float*)d_in[0];
  const int*  mk  = (const int*)d_in[1];
  const float* W1 = (const float*)d_in[2];
  const float* W2 = (const float*)d_in[3];
  const float* W3 = (const float*)d_in[4];
  const float* w  = (const float*)d_in[5];
  float* out = (float*)d_out;

  char* ws = (char*)d_ws;
  unsigned short* X2 = (unsigned short*)ws;                 // 16384*256  = 8 MB
  unsigned short* Wc = X2 + (size_t)16384 * 256;            //   576*256  = 288 KB
  unsigned short* Q2 = Wc + (size_t)576 * 256;              // 32*8*512*64 = 16 MB
  unsigned short* K2 = Q2 + (size_t)32 * 8 * 512 * 64;      // 16 MB
  float* Vw  = (float*)(K2 + (size_t)32 * 8 * 512 * 64);    // 512 KB
  float* vws = Vw + (size_t)32 * 8 * 512;                   // 512 KB

  convert_kernel<<<dim3(1057), dim3(256), 0, stream>>>(X, W1, W2, W3, w, X2, Wc);
  proj_kernel<<<dim3(128, 9), dim3(256), 0, stream>>>(X2, Wc, Q2, K2, Vw);
  attn_kernel<<<dim3(2, 8, 32), dim3(512), 0, stream>>>(Q2, K2, Vw, mk, vws);
  final_kernel<<<dim3(32), dim3(512), 0, stream>>>(vws, mk, out);
}